// Round 1
// baseline (230.595 us; speedup 1.0000x reference)
//
#include <hip/hip_runtime.h>

typedef unsigned short u16;
typedef __bf16 bf16x8 __attribute__((ext_vector_type(8)));
typedef float f32x4 __attribute__((ext_vector_type(4)));

#define N_ 16384
#define SCALE 0.35355339059327379f   // 64^-0.25

__device__ __forceinline__ u16 f2bf(float f){
  union { float f; unsigned int i; } v; v.f = f;
  unsigned int b = v.i;
  return (u16)((b + 0x7FFFu + ((b >> 16) & 1u)) >> 16);
}
__device__ __forceinline__ unsigned int pack2bf(float a, float b){
  return ((unsigned int)f2bf(b) << 16) | (unsigned int)f2bf(a);
}

// ---------------------------------------------------------------------------
// prep: A/B-frag order for 16x16x32: lane = (row&15)|(((k>>3)&3)<<4), elem=k&7.
// wkvf: f = (h*8 + jt)*4 + ks, row j = 16*jt + (l&15) of [SCALE*Wk_h; Wv_h]
// wqf:  f = (h*4 + dt)*4 + ks, row d = 16*dt + (l&15) of SCALE*Wq_h
// ---------------------------------------------------------------------------
__global__ __launch_bounds__(256) void prep(const float* __restrict__ Wq,
    const float* __restrict__ bq, const float* __restrict__ Wk,
    const float* __restrict__ bk, const float* __restrict__ Wv,
    const float* __restrict__ bv, u16* __restrict__ wkvf, u16* __restrict__ wqf,
    float* __restrict__ bkv, float* __restrict__ bqs){
  const int T = blockIdx.x * 256 + threadIdx.x;   // 0..24575
  if (T < 1024){
    int jj = T & 127, h = T >> 7;
    bkv[T] = (jj < 64) ? SCALE * bk[h * 64 + jj] : bv[h * 64 + jj - 64];
  } else if (T < 1536){
    bqs[T - 1024] = SCALE * bq[T - 1024];
  }
  const float* src; float sc; u16* dst;
  if (T < 16384){
    int l = T & 63, f = T >> 6;
    int ks = f & 3, jt = (f >> 2) & 7, h = f >> 5;
    int jj = 16 * jt + (l & 15);
    int k0 = ks * 32 + (l >> 4) * 8;
    if (jj < 64){ src = Wk + (size_t)(h * 64 + jj) * 128 + k0; sc = SCALE; }
    else        { src = Wv + (size_t)(h * 64 + jj - 64) * 128 + k0; sc = 1.f; }
    dst = wkvf + (size_t)f * 512 + l * 8;
  } else {
    int T2 = T - 16384;
    int l = T2 & 63, f = T2 >> 6;
    int ks = f & 3, dt = (f >> 2) & 3, h = f >> 4;
    int d = 16 * dt + (l & 15);
    int k0 = ks * 32 + (l >> 4) * 8;
    src = Wq + (size_t)(h * 64 + d) * 128 + k0; sc = SCALE;
    dst = wqf + (size_t)f * 512 + l * 8;
  }
  float4 a = *(const float4*)src, c = *(const float4*)(src + 4);
  ushort4 o0, o1;
  o0.x = f2bf(sc * a.x); o0.y = f2bf(sc * a.y); o0.z = f2bf(sc * a.z); o0.w = f2bf(sc * a.w);
  o1.x = f2bf(sc * c.x); o1.y = f2bf(sc * c.y); o1.z = f2bf(sc * c.z); o1.w = f2bf(sc * c.w);
  *(ushort4*)dst = o0; *(ushort4*)(dst + 4) = o1;
}

// ---------------------------------------------------------------------------
// convx v2 (LDS-free, PRE-SWIZZLED output): xt[b][t][ (g^(t&15)) 8-elem group ].
// Reads x along tokens (float2, fully coalesced), packs bf16 in regs, writes
// 16-B groups at swizzled positions. Consumers read MFMA A/B-frags DIRECTLY
// from xt: lane(q,r15) reads group (ks*4+q)^r15 of row t -> per 16 rows that
// is one full 64-B line per row = perfectly coalesced.
// ---------------------------------------------------------------------------
__global__ __launch_bounds__(256) void convx(const float* __restrict__ x,
                                             u16* __restrict__ xt){
  const int tid = threadIdx.x;
  const int b = blockIdx.y;
  const int kq = tid >> 6;                       // wave = k-quarter (32 k)
  const int t0 = blockIdx.x * 128 + 2 * (tid & 63);  // 2 tokens / thread
  const float* xp = x + (size_t)(b * 128 + kq * 32) * N_ + t0;
  u16* dst = xt + (size_t)(b * N_ + t0) * 128;
#pragma unroll
  for (int gi = 0; gi < 4; gi++){
    float2 v[8];
#pragma unroll
    for (int j = 0; j < 8; j++)
      v[j] = *(const float2*)(xp + (size_t)(gi * 8 + j) * N_);
    const int g = kq * 4 + gi;                   // global 8-elem k-group
    {
      uint4 o;
      o.x = pack2bf(v[0].x, v[1].x); o.y = pack2bf(v[2].x, v[3].x);
      o.z = pack2bf(v[4].x, v[5].x); o.w = pack2bf(v[6].x, v[7].x);
      *(uint4*)(dst + ((g ^ (t0 & 15)) * 8)) = o;
    }
    {
      uint4 o;
      o.x = pack2bf(v[0].y, v[1].y); o.y = pack2bf(v[2].y, v[3].y);
      o.z = pack2bf(v[4].y, v[5].y); o.w = pack2bf(v[6].y, v[7].y);
      const int t = t0 + 1;
      *(uint4*)(dst + 128 + ((g ^ (t & 15)) * 8)) = o;
    }
  }
}

// ---------------------------------------------------------------------------
// kvctx v3: NO x-staging. MFMA1 A-frags load directly from pre-swizzled xt
// (fully coalesced, L2/L3-resident) overlapping MFMA issue. Barriers per
// sub: 3 -> 2 (sekv producer/consumer only). LDS: sekv 32 KiB (+fb overlay).
// ---------------------------------------------------------------------------
__global__ __launch_bounds__(256, 2) void kvctx(const u16* __restrict__ xt,
    const u16* __restrict__ wkvf, const float* __restrict__ bkv,
    float* __restrict__ pctx, float* __restrict__ prs){
  __shared__ u16 smem[32768];   // [0,16384): sekv[128j][128t]; epilogue fb = 64 KiB
  const int tid = threadIdx.x;
  const int chunk = blockIdx.x, h = blockIdx.y, b = blockIdx.z;
  const int w = tid >> 6, l = tid & 63, r15 = l & 15, q = l >> 4;
  const int th = w & 1, jh = w >> 1;

  bf16x8 wf[4][4];
#pragma unroll
  for (int ni = 0; ni < 4; ni++)
#pragma unroll
    for (int ks = 0; ks < 4; ks++)
      wf[ni][ks] = *(const bf16x8*)(wkvf +
          (size_t)((h * 8 + 4 * jh + ni) * 4 + ks) * 512 + l * 8);
  float barr[4];
#pragma unroll
  for (int ni = 0; ni < 4; ni++)
    barr[ni] = bkv[h * 128 + jh * 64 + 16 * ni + r15];

  const size_t tok0 = (size_t)b * N_ + chunk * 512;
  f32x4 acc2[4][4] = {};
  float rs[4] = {0.f, 0.f, 0.f, 0.f};
  u16* sekv = smem;

  for (int sub = 0; sub < 4; sub++){
    f32x4 acc1[4][4] = {};
#pragma unroll
    for (int ks = 0; ks < 4; ks++){
      bf16x8 xa[4];
#pragma unroll
      for (int mi = 0; mi < 4; mi++){
        const size_t trow = tok0 + sub * 128 + th * 64 + 16 * mi + r15;
        xa[mi] = *(const bf16x8*)(xt + trow * 128 + (((ks * 4 + q) ^ r15) * 8));
      }
#pragma unroll
      for (int mi = 0; mi < 4; mi++)
#pragma unroll
        for (int ni = 0; ni < 4; ni++)
          acc1[mi][ni] = __builtin_amdgcn_mfma_f32_16x16x32_bf16(
              xa[mi], wf[ni][ks], acc1[mi][ni], 0, 0, 0);
    }
#pragma unroll
    for (int ni = 0; ni < 4; ni++){
      const float bb = barr[ni];
      const int j = jh * 64 + 16 * ni + r15;
      float ps = 0.f;
#pragma unroll
      for (int mi = 0; mi < 4; mi++){
        float vals[4];
#pragma unroll
        for (int r = 0; r < 4; r++) vals[r] = acc1[mi][ni][r] + bb;
        if (jh == 0){
#pragma unroll
          for (int r = 0; r < 4; r++){ vals[r] = __expf(vals[r]); ps += vals[r]; }
        }
        uint2 pk;
        pk.x = pack2bf(vals[0], vals[1]);
        pk.y = pack2bf(vals[2], vals[3]);
        int g8 = 16 * th + 4 * mi + q;
        int g8s = g8 ^ (2 * r15);
        *(uint2*)&sekv[j * 128 + g8s * 4] = pk;
      }
      if (jh == 0){
        ps += __shfl_xor(ps, 16); ps += __shfl_xor(ps, 32);
        rs[ni] += ps;
      }
    }
    __syncthreads();        // sekv visible to all waves
    {
      bf16x8 ka[4], va[4];
      const int g8s = (8 * w + 2 * q) ^ (2 * r15);
#pragma unroll
      for (int mi2 = 0; mi2 < 4; mi2++){
        int d = 16 * mi2 + r15;
        ka[mi2] = *(const bf16x8*)&sekv[d * 128 + g8s * 4];
      }
#pragma unroll
      for (int ni2 = 0; ni2 < 4; ni2++){
        int e = 16 * ni2 + r15;
        va[ni2] = *(const bf16x8*)&sekv[(64 + e) * 128 + g8s * 4];
      }
#pragma unroll
      for (int mi2 = 0; mi2 < 4; mi2++)
#pragma unroll
        for (int ni2 = 0; ni2 < 4; ni2++)
          acc2[mi2][ni2] = __builtin_amdgcn_mfma_f32_16x16x32_bf16(
              ka[mi2], va[ni2], acc2[mi2][ni2], 0, 0, 0);
    }
    __syncthreads();        // sekv free for next sub's writes (or fb overlay)
  }
  float* fb = (float*)smem;
#pragma unroll
  for (int mi2 = 0; mi2 < 4; mi2++)
#pragma unroll
    for (int ni2 = 0; ni2 < 4; ni2++)
#pragma unroll
      for (int r = 0; r < 4; r++){
        int d = 16 * mi2 + 4 * q + r, e = 16 * ni2 + r15;
        fb[w * 4096 + d * 64 + e] = acc2[mi2][ni2][r];
      }
  __syncthreads();
  {
    float* dst = pctx + ((size_t)((b * 8 + h) * 32 + chunk)) * 4096 + tid * 16;
#pragma unroll
    for (int i = 0; i < 4; i++){
      int o = tid * 16 + 4 * i;
      float4 a = *(const float4*)(fb + o);
      float4 c = *(const float4*)(fb + 4096 + o);
      float4 d = *(const float4*)(fb + 8192 + o);
      float4 e = *(const float4*)(fb + 12288 + o);
      float4 s;
      s.x = a.x + c.x + d.x + e.x; s.y = a.y + c.y + d.y + e.y;
      s.z = a.z + c.z + d.z + e.z; s.w = a.w + c.w + d.w + e.w;
      *(float4*)(dst + 4 * i) = s;
    }
  }
  if (jh == 0 && q == 0){
    float* rb = prs + ((size_t)((b * 8 + h) * 32 + chunk)) * 128 + th * 64;
#pragma unroll
    for (int ni = 0; ni < 4; ni++) rb[16 * ni + r15] = rs[ni];
  }
}

// ---------------------------------------------------------------------------
// ctxred (unchanged): grid (32 bh, 8 slices).
// ---------------------------------------------------------------------------
__global__ __launch_bounds__(256) void ctxred(const float* __restrict__ pctx,
    const float* __restrict__ prs, float* __restrict__ ctx,
    float* __restrict__ rowsum){
  const int bh = blockIdx.x, s = blockIdx.y, tid = threadIdx.x;
  const float2* base = (const float2*)(pctx + (size_t)bh * 32 * 4096 + s * 512) + tid;
  float2 acc = {0.f, 0.f};
#pragma unroll 4
  for (int t = 0; t < 32; t++){
    float2 v = base[t * 2048];
    acc.x += v.x; acc.y += v.y;
  }
  *((float2*)(ctx + (size_t)bh * 4096 + s * 512) + tid) = acc;
  if (s == 0 && tid < 64){
    const float* rb = prs + (size_t)bh * 32 * 128 + tid;
    float sm = 0.f;
    for (int t = 0; t < 32; t++) sm += rb[t * 128] + rb[t * 128 + 64];
    rowsum[bh * 64 + tid] = sm;
  }
}

// ---------------------------------------------------------------------------
// mker (unchanged): M[c][d] = (1/rowsum[d]) * sum_e Wo[c][h*64+e] * ctx[b][h][d][e]
// ---------------------------------------------------------------------------
__global__ __launch_bounds__(256) void mker(const float* __restrict__ ctx,
    const float* __restrict__ Wo, const float* __restrict__ rowsum,
    u16* __restrict__ mtf){
  __shared__ float ctxh[64][68];
  __shared__ float woht[64][132];
  const int tid = threadIdx.x;
  const int h = blockIdx.x, b = blockIdx.y;
  const int bh = b * 8 + h;
  const int e4 = tid & 15, r0 = tid >> 4;
#pragma unroll
  for (int p = 0; p < 4; p++){
    int d = r0 + p * 16;
    float4 v = *(const float4*)(ctx + ((size_t)bh * 64 + d) * 64 + 4 * e4);
    *(float4*)&ctxh[d][4 * e4] = v;
  }
#pragma unroll
  for (int p = 0; p < 8; p++){
    int c = r0 + p * 16;
    float4 v = *(const float4*)(Wo + (size_t)c * 512 + h * 64 + 4 * e4);
    woht[4 * e4 + 0][c] = v.x; woht[4 * e4 + 1][c] = v.y;
    woht[4 * e4 + 2][c] = v.z; woht[4 * e4 + 3][c] = v.w;
  }
  __syncthreads();
  const int cg = tid & 3, d = tid >> 2;
  const float inv = 1.f / rowsum[bh * 64 + d];
  float acc[32];
#pragma unroll
  for (int cc = 0; cc < 32; cc++) acc[cc] = 0.f;
  for (int e = 0; e < 64; e++){
    float cv = ctxh[d][e];
#pragma unroll
    for (int cc = 0; cc < 32; cc++) acc[cc] += cv * woht[e][cg + 4 * cc];
  }
  const int ks = d >> 5, lq = ((d >> 3) & 3) << 4, el = d & 7;
#pragma unroll
  for (int cc = 0; cc < 32; cc++){
    int c = cg + 4 * cc;
    mtf[((size_t)(bh * 8 + (c >> 4)) * 2 + ks) * 512 + ((c & 15) | lq) * 8 + el]
        = f2bf(inv * acc[cc]);
  }
}

// ---------------------------------------------------------------------------
// qout v3: 128 tokens/block (32/wave), ZERO barriers. x B-frags hoisted into
// regs once per wave (direct from pre-swizzled xt, h-independent). Per head:
// 32 weight-frag loads feed 64 MFMAs (was 32:32). smP stays wave-private.
// ---------------------------------------------------------------------------
__global__ __launch_bounds__(256, 2) void qout(const u16* __restrict__ xt,
    const u16* __restrict__ wqf, const float* __restrict__ bqs,
    const u16* __restrict__ mtf, const float* __restrict__ bo,
    float* __restrict__ out){
  __shared__ u16 smP[4][32 * 64]; // per-wave p[32t][64d]  (16 KiB total)
  const int tid = threadIdx.x;
  const int tt = blockIdx.x, b = blockIdx.y;
  const int w = tid >> 6, l = tid & 63, r15 = l & 15, q = l >> 4;
  const int t0 = tt * 128;
  const int m7 = 2 * (r15 & 7);

  // hoist x B-frags for this wave's 32 tokens: xb[ks][u]
  bf16x8 xb[4][2];
#pragma unroll
  for (int ks = 0; ks < 4; ks++)
#pragma unroll
    for (int u = 0; u < 2; u++){
      const int t = t0 + w * 32 + u * 16 + r15;
      xb[ks][u] = *(const bf16x8*)(xt + (size_t)(b * N_ + t) * 128 +
                                   (((ks * 4 + q) ^ r15) * 8));
    }

  u16* sp = smP[w];
  f32x4 acc3[8][2] = {};
  for (int h = 0; h < 8; h++){
    float4 bq4[4];
#pragma unroll
    for (int mi = 0; mi < 4; mi++)
      bq4[mi] = *(const float4*)(bqs + h * 64 + 16 * mi + 4 * q);
    // MFMA1: D[d 64][t 32], K=128; A = wq frags (global), B = xb (regs)
    f32x4 acc1[4][2] = {};
#pragma unroll
    for (int ks = 0; ks < 4; ks++){
      bf16x8 wqv[4];
#pragma unroll
      for (int mi = 0; mi < 4; mi++)
        wqv[mi] = *(const bf16x8*)(wqf +
            (size_t)((h * 4 + mi) * 4 + ks) * 512 + l * 8);
#pragma unroll
      for (int mi = 0; mi < 4; mi++)
#pragma unroll
        for (int u = 0; u < 2; u++)
          acc1[mi][u] = __builtin_amdgcn_mfma_f32_16x16x32_bf16(
              wqv[mi], xb[ks][u], acc1[mi][u], 0, 0, 0);
    }
    // exp + in-wave colsum + normalized p store (wave-private, per token tile)
#pragma unroll
    for (int u = 0; u < 2; u++){
      float ps = 0.f;
#pragma unroll
      for (int mi = 0; mi < 4; mi++)
#pragma unroll
        for (int r = 0; r < 4; r++){
          float bqv = (r == 0) ? bq4[mi].x : (r == 1) ? bq4[mi].y
                    : (r == 2) ? bq4[mi].z : bq4[mi].w;
          float e = __expf(acc1[mi][u][r] + bqv);
          acc1[mi][u][r] = e; ps += e;
        }
      ps += __shfl_xor(ps, 16); ps += __shfl_xor(ps, 32);
      const float ci = 1.f / ps;
#pragma unroll
      for (int mi = 0; mi < 4; mi++){
        uint2 pk;
        pk.x = pack2bf(acc1[mi][u][0] * ci, acc1[mi][u][1] * ci);
        pk.y = pack2bf(acc1[mi][u][2] * ci, acc1[mi][u][3] * ci);
        int g8s = (4 * mi + q) ^ m7;
        *(uint2*)&sp[(u * 16 + r15) * 64 + g8s * 4] = pk;
      }
    }
    // MFMA2: out[c 128][t 32] += M_h · p, K=64
#pragma unroll
    for (int ks2 = 0; ks2 < 2; ks2++){
      const int g8s = (8 * ks2 + 2 * q) ^ m7;
      bf16x8 pb[2];
#pragma unroll
      for (int u = 0; u < 2; u++)
        pb[u] = *(const bf16x8*)&sp[(u * 16 + r15) * 64 + g8s * 4];
#pragma unroll
      for (int half = 0; half < 2; half++){
        bf16x8 mf[4];
#pragma unroll
        for (int mm = 0; mm < 4; mm++)
          mf[mm] = *(const bf16x8*)(mtf +
              ((size_t)((b * 8 + h) * 8 + half * 4 + mm) * 2 + ks2) * 512 + l * 8);
#pragma unroll
        for (int mm = 0; mm < 4; mm++)
#pragma unroll
          for (int u = 0; u < 2; u++)
            acc3[half * 4 + mm][u] = __builtin_amdgcn_mfma_f32_16x16x32_bf16(
                mf[mm], pb[u], acc3[half * 4 + mm][u], 0, 0, 0);
      }
    }
  }
#pragma unroll
  for (int mi = 0; mi < 8; mi++){
    float4 bv = *(const float4*)(bo + 16 * mi + 4 * q);
    float bs[4] = {bv.x, bv.y, bv.z, bv.w};
#pragma unroll
    for (int u = 0; u < 2; u++)
#pragma unroll
      for (int r = 0; r < 4; r++){
        int c = 16 * mi + 4 * q + r;
        int t = t0 + w * 32 + u * 16 + r15;
        out[(size_t)(b * 128 + c) * N_ + t] = acc3[mi][u][r] + bs[r];
      }
  }
}

// ---------------------------------------------------------------------------
extern "C" void kernel_launch(void* const* d_in, const int* in_sizes, int n_in,
                              void* d_out, int out_size, void* d_ws, size_t ws_size,
                              hipStream_t stream){
  const float* x  = (const float*)d_in[0];
  const float* Wq = (const float*)d_in[1];
  const float* bq = (const float*)d_in[2];
  const float* Wk = (const float*)d_in[3];
  const float* bk = (const float*)d_in[4];
  const float* Wv = (const float*)d_in[5];
  const float* bv = (const float*)d_in[6];
  const float* Wo = (const float*)d_in[7];
  const float* bo = (const float*)d_in[8];
  float* out = (float*)d_out;

  char* ws = (char*)d_ws;
  u16*   xt     = (u16*)ws;                         // 16 MiB (pre-swizzled)
  u16*   wkvf   = (u16*)(ws + 16777216);            // 256 KiB
  u16*   wqf    = (u16*)(ws + 17039360);            // 128 KiB
  u16*   mtf    = (u16*)(ws + 17170432);            // 512 KiB
  float* bkv    = (float*)(ws + 17694720);          // 4 KiB
  float* bqs    = (float*)(ws + 17698816);          // 2 KiB
  float* rowsum = (float*)(ws + 17700864);          // 8 KiB
  float* ctx    = (float*)(ws + 17709056);          // 512 KiB
  float* pctx   = (float*)(ws + 18233344);          // 16 MiB
  float* prs    = (float*)(ws + 35010560);          // 512 KiB

  prep <<<96, 256, 0, stream>>>(Wq, bq, Wk, bk, Wv, bv, wkvf, wqf, bkv, bqs);
  convx<<<dim3(128, 4), 256, 0, stream>>>(x, xt);
  kvctx<<<dim3(32, 8, 4), 256, 0, stream>>>(xt, wkvf, bkv, pctx, prs);
  ctxred<<<dim3(32, 8), 256, 0, stream>>>(pctx, prs, ctx, rowsum);
  mker <<<dim3(8, 4), 256, 0, stream>>>(ctx, Wo, rowsum, mtf);
  qout <<<dim3(128, 4), 256, 0, stream>>>(xt, wqf, bqs, mtf, bo, out);
}

// Round 2
// 202.806 us; speedup vs baseline: 1.1370x; 1.1370x over previous
//
#include <hip/hip_runtime.h>

typedef unsigned short u16;
typedef __bf16 bf16x8 __attribute__((ext_vector_type(8)));
typedef float f32x4 __attribute__((ext_vector_type(4)));

#define N_ 16384
#define SCALE 0.35355339059327379f   // 64^-0.25

__device__ __forceinline__ u16 f2bf(float f){
  union { float f; unsigned int i; } v; v.f = f;
  unsigned int b = v.i;
  return (u16)((b + 0x7FFFu + ((b >> 16) & 1u)) >> 16);
}
__device__ __forceinline__ unsigned int pack2bf(float a, float b){
  return ((unsigned int)f2bf(b) << 16) | (unsigned int)f2bf(a);
}

// ---------------------------------------------------------------------------
// prep: A/B-frag order for 16x16x32: lane = (row&15)|(((k>>3)&3)<<4), elem=k&7.
// wkvf: f = (h*8 + jt)*4 + ks, row j = 16*jt + (l&15) of [SCALE*Wk_h; Wv_h]
// wqf:  f = (h*4 + dt)*4 + ks, row d = 16*dt + (l&15) of SCALE*Wq_h
// ---------------------------------------------------------------------------
__global__ __launch_bounds__(256) void prep(const float* __restrict__ Wq,
    const float* __restrict__ bq, const float* __restrict__ Wk,
    const float* __restrict__ bk, const float* __restrict__ Wv,
    const float* __restrict__ bv, u16* __restrict__ wkvf, u16* __restrict__ wqf,
    float* __restrict__ bkv, float* __restrict__ bqs){
  const int T = blockIdx.x * 256 + threadIdx.x;   // 0..24575
  if (T < 1024){
    int jj = T & 127, h = T >> 7;
    bkv[T] = (jj < 64) ? SCALE * bk[h * 64 + jj] : bv[h * 64 + jj - 64];
  } else if (T < 1536){
    bqs[T - 1024] = SCALE * bq[T - 1024];
  }
  const float* src; float sc; u16* dst;
  if (T < 16384){
    int l = T & 63, f = T >> 6;
    int ks = f & 3, jt = (f >> 2) & 7, h = f >> 5;
    int jj = 16 * jt + (l & 15);
    int k0 = ks * 32 + (l >> 4) * 8;
    if (jj < 64){ src = Wk + (size_t)(h * 64 + jj) * 128 + k0; sc = SCALE; }
    else        { src = Wv + (size_t)(h * 64 + jj - 64) * 128 + k0; sc = 1.f; }
    dst = wkvf + (size_t)f * 512 + l * 8;
  } else {
    int T2 = T - 16384;
    int l = T2 & 63, f = T2 >> 6;
    int ks = f & 3, dt = (f >> 2) & 3, h = f >> 4;
    int d = 16 * dt + (l & 15);
    int k0 = ks * 32 + (l >> 4) * 8;
    src = Wq + (size_t)(h * 64 + d) * 128 + k0; sc = SCALE;
    dst = wqf + (size_t)f * 512 + l * 8;
  }
  float4 a = *(const float4*)src, c = *(const float4*)(src + 4);
  ushort4 o0, o1;
  o0.x = f2bf(sc * a.x); o0.y = f2bf(sc * a.y); o0.z = f2bf(sc * a.z); o0.w = f2bf(sc * a.w);
  o1.x = f2bf(sc * c.x); o1.y = f2bf(sc * c.y); o1.z = f2bf(sc * c.z); o1.w = f2bf(sc * c.w);
  *(ushort4*)dst = o0; *(ushort4*)(dst + 4) = o1;
}

// ---------------------------------------------------------------------------
// convx (LDS-free, PRE-SWIZZLED output): row t holds 8-elem k-group g at
// position g^(t&15). Consumers read MFMA frags directly / stage verbatim.
// ---------------------------------------------------------------------------
__global__ __launch_bounds__(256) void convx(const float* __restrict__ x,
                                             u16* __restrict__ xt){
  const int tid = threadIdx.x;
  const int b = blockIdx.y;
  const int kq = tid >> 6;                       // wave = k-quarter (32 k)
  const int t0 = blockIdx.x * 128 + 2 * (tid & 63);  // 2 tokens / thread
  const float* xp = x + (size_t)(b * 128 + kq * 32) * N_ + t0;
  u16* dst = xt + (size_t)(b * N_ + t0) * 128;
#pragma unroll
  for (int gi = 0; gi < 4; gi++){
    float2 v[8];
#pragma unroll
    for (int j = 0; j < 8; j++)
      v[j] = *(const float2*)(xp + (size_t)(gi * 8 + j) * N_);
    const int g = kq * 4 + gi;                   // global 8-elem k-group
    {
      uint4 o;
      o.x = pack2bf(v[0].x, v[1].x); o.y = pack2bf(v[2].x, v[3].x);
      o.z = pack2bf(v[4].x, v[5].x); o.w = pack2bf(v[6].x, v[7].x);
      *(uint4*)(dst + ((g ^ (t0 & 15)) * 8)) = o;
    }
    {
      uint4 o;
      o.x = pack2bf(v[0].y, v[1].y); o.y = pack2bf(v[2].y, v[3].y);
      o.z = pack2bf(v[4].y, v[5].y); o.w = pack2bf(v[6].y, v[7].y);
      const int t = t0 + 1;
      *(uint4*)(dst + 128 + ((g ^ (t & 15)) * 8)) = o;
    }
  }
}

// ---------------------------------------------------------------------------
// kvctx v4: LDS staging restored, but via global_load_lds (verbatim copy of
// pre-swizzled xt rows: LDS dest = wave-uniform base + lane*16). Staging for
// sub+1 is issued right after the sekv barrier and flies under MFMA2; the
// next __syncthreads drains vmcnt. 2 barriers/sub (was 3), zero staging VGPRs.
// ---------------------------------------------------------------------------
__global__ __launch_bounds__(256, 2) void kvctx(const u16* __restrict__ xt,
    const u16* __restrict__ wkvf, const float* __restrict__ bkv,
    float* __restrict__ pctx, float* __restrict__ prs){
  __shared__ u16 smem[32768];   // sx bytes [0,32768) ; sekv bytes [32768,65536); fb overlay
  const int tid = threadIdx.x;
  const int chunk = blockIdx.x, h = blockIdx.y, b = blockIdx.z;
  const int w = tid >> 6, l = tid & 63, r15 = l & 15, q = l >> 4;
  const int th = w & 1, jh = w >> 1;

  bf16x8 wf[4][4];
#pragma unroll
  for (int ni = 0; ni < 4; ni++)
#pragma unroll
    for (int ks = 0; ks < 4; ks++)
      wf[ni][ks] = *(const bf16x8*)(wkvf +
          (size_t)((h * 8 + 4 * jh + ni) * 4 + ks) * 512 + l * 8);
  float barr[4];
#pragma unroll
  for (int ni = 0; ni < 4; ni++)
    barr[ni] = bkv[h * 128 + jh * 64 + 16 * ni + r15];

  const size_t tok0 = (size_t)b * N_ + chunk * 512;
  const char* gbase = (const char*)(xt + tok0 * 128);  // 512 rows x 256 B
  u16* sekv = smem + 16384;

  // async stage of x sub-tile (32 KiB): wave w copies bytes [8192w, 8192w+8192)
#define STAGE(sub_)                                                            \
  {                                                                            \
    const char* gs = gbase + (size_t)(sub_)*32768 + w * 8192 + l * 16;         \
    char* ls = (char*)smem + w * 8192;                                         \
    _Pragma("unroll")                                                          \
    for (int p = 0; p < 8; p++)                                                \
      __builtin_amdgcn_global_load_lds(                                        \
          (const __attribute__((address_space(1))) void*)(gs + p * 1024),      \
          (__attribute__((address_space(3))) void*)(ls + p * 1024), 16, 0, 0); \
  }

  STAGE(0);
  __syncthreads();   // drains vmcnt: sub0 x-tile ready

  f32x4 acc2[4][4] = {};
  float rs[4] = {0.f, 0.f, 0.f, 0.f};

  for (int sub = 0; sub < 4; sub++){
    f32x4 acc1[4][4] = {};
#pragma unroll
    for (int ks = 0; ks < 4; ks++){
      bf16x8 xa[4];
#pragma unroll
      for (int mi = 0; mi < 4; mi++){
        int t = th * 64 + 16 * mi + r15;
        xa[mi] = *(const bf16x8*)&smem[t * 128 + (((ks * 4 + q) ^ r15) * 8)];
      }
#pragma unroll
      for (int mi = 0; mi < 4; mi++)
#pragma unroll
        for (int ni = 0; ni < 4; ni++)
          acc1[mi][ni] = __builtin_amdgcn_mfma_f32_16x16x32_bf16(
              xa[mi], wf[ni][ks], acc1[mi][ni], 0, 0, 0);
    }
#pragma unroll
    for (int ni = 0; ni < 4; ni++){
      const float bb = barr[ni];
      const int j = jh * 64 + 16 * ni + r15;
      float ps = 0.f;
#pragma unroll
      for (int mi = 0; mi < 4; mi++){
        float vals[4];
#pragma unroll
        for (int r = 0; r < 4; r++) vals[r] = acc1[mi][ni][r] + bb;
        if (jh == 0){
#pragma unroll
          for (int r = 0; r < 4; r++){ vals[r] = __expf(vals[r]); ps += vals[r]; }
        }
        uint2 pk;
        pk.x = pack2bf(vals[0], vals[1]);
        pk.y = pack2bf(vals[2], vals[3]);
        int g8 = 16 * th + 4 * mi + q;
        int g8s = g8 ^ (2 * r15);
        *(uint2*)&sekv[j * 128 + g8s * 4] = pk;
      }
      if (jh == 0){
        ps += __shfl_xor(ps, 16); ps += __shfl_xor(ps, 32);
        rs[ni] += ps;
      }
    }
    __syncthreads();             // B1: sekv ready; sx consumed by all waves
    if (sub < 3) STAGE(sub + 1); // overwrite sx async, flies under MFMA2
    {
      bf16x8 ka[4], va[4];
      const int g8s = (8 * w + 2 * q) ^ (2 * r15);
#pragma unroll
      for (int mi2 = 0; mi2 < 4; mi2++){
        int d = 16 * mi2 + r15;
        ka[mi2] = *(const bf16x8*)&sekv[d * 128 + g8s * 4];
      }
#pragma unroll
      for (int ni2 = 0; ni2 < 4; ni2++){
        int e = 16 * ni2 + r15;
        va[ni2] = *(const bf16x8*)&sekv[(64 + e) * 128 + g8s * 4];
      }
#pragma unroll
      for (int mi2 = 0; mi2 < 4; mi2++)
#pragma unroll
        for (int ni2 = 0; ni2 < 4; ni2++)
          acc2[mi2][ni2] = __builtin_amdgcn_mfma_f32_16x16x32_bf16(
              ka[mi2], va[ni2], acc2[mi2][ni2], 0, 0, 0);
    }
    __syncthreads();             // B2: vmcnt drained (sx ready); sekv consumed
  }
#undef STAGE
  float* fb = (float*)smem;
#pragma unroll
  for (int mi2 = 0; mi2 < 4; mi2++)
#pragma unroll
    for (int ni2 = 0; ni2 < 4; ni2++)
#pragma unroll
      for (int r = 0; r < 4; r++){
        int d = 16 * mi2 + 4 * q + r, e = 16 * ni2 + r15;
        fb[w * 4096 + d * 64 + e] = acc2[mi2][ni2][r];
      }
  __syncthreads();
  {
    float* dst = pctx + ((size_t)((b * 8 + h) * 32 + chunk)) * 4096 + tid * 16;
#pragma unroll
    for (int i = 0; i < 4; i++){
      int o = tid * 16 + 4 * i;
      float4 a = *(const float4*)(fb + o);
      float4 c = *(const float4*)(fb + 4096 + o);
      float4 d = *(const float4*)(fb + 8192 + o);
      float4 e = *(const float4*)(fb + 12288 + o);
      float4 s;
      s.x = a.x + c.x + d.x + e.x; s.y = a.y + c.y + d.y + e.y;
      s.z = a.z + c.z + d.z + e.z; s.w = a.w + c.w + d.w + e.w;
      *(float4*)(dst + 4 * i) = s;
    }
  }
  if (jh == 0 && q == 0){
    float* rb = prs + ((size_t)((b * 8 + h) * 32 + chunk)) * 128 + th * 64;
#pragma unroll
    for (int ni = 0; ni < 4; ni++) rb[16 * ni + r15] = rs[ni];
  }
}

// ---------------------------------------------------------------------------
// ctxred (unchanged): grid (32 bh, 8 slices).
// ---------------------------------------------------------------------------
__global__ __launch_bounds__(256) void ctxred(const float* __restrict__ pctx,
    const float* __restrict__ prs, float* __restrict__ ctx,
    float* __restrict__ rowsum){
  const int bh = blockIdx.x, s = blockIdx.y, tid = threadIdx.x;
  const float2* base = (const float2*)(pctx + (size_t)bh * 32 * 4096 + s * 512) + tid;
  float2 acc = {0.f, 0.f};
#pragma unroll 4
  for (int t = 0; t < 32; t++){
    float2 v = base[t * 2048];
    acc.x += v.x; acc.y += v.y;
  }
  *((float2*)(ctx + (size_t)bh * 4096 + s * 512) + tid) = acc;
  if (s == 0 && tid < 64){
    const float* rb = prs + (size_t)bh * 32 * 128 + tid;
    float sm = 0.f;
    for (int t = 0; t < 32; t++) sm += rb[t * 128] + rb[t * 128 + 64];
    rowsum[bh * 64 + tid] = sm;
  }
}

// ---------------------------------------------------------------------------
// mker (unchanged): M[c][d] = (1/rowsum[d]) * sum_e Wo[c][h*64+e] * ctx[b][h][d][e]
// ---------------------------------------------------------------------------
__global__ __launch_bounds__(256) void mker(const float* __restrict__ ctx,
    const float* __restrict__ Wo, const float* __restrict__ rowsum,
    u16* __restrict__ mtf){
  __shared__ float ctxh[64][68];
  __shared__ float woht[64][132];
  const int tid = threadIdx.x;
  const int h = blockIdx.x, b = blockIdx.y;
  const int bh = b * 8 + h;
  const int e4 = tid & 15, r0 = tid >> 4;
#pragma unroll
  for (int p = 0; p < 4; p++){
    int d = r0 + p * 16;
    float4 v = *(const float4*)(ctx + ((size_t)bh * 64 + d) * 64 + 4 * e4);
    *(float4*)&ctxh[d][4 * e4] = v;
  }
#pragma unroll
  for (int p = 0; p < 8; p++){
    int c = r0 + p * 16;
    float4 v = *(const float4*)(Wo + (size_t)c * 512 + h * 64 + 4 * e4);
    woht[4 * e4 + 0][c] = v.x; woht[4 * e4 + 1][c] = v.y;
    woht[4 * e4 + 2][c] = v.z; woht[4 * e4 + 3][c] = v.w;
  }
  __syncthreads();
  const int cg = tid & 3, d = tid >> 2;
  const float inv = 1.f / rowsum[bh * 64 + d];
  float acc[32];
#pragma unroll
  for (int cc = 0; cc < 32; cc++) acc[cc] = 0.f;
  for (int e = 0; e < 64; e++){
    float cv = ctxh[d][e];
#pragma unroll
    for (int cc = 0; cc < 32; cc++) acc[cc] += cv * woht[e][cg + 4 * cc];
  }
  const int ks = d >> 5, lq = ((d >> 3) & 3) << 4, el = d & 7;
#pragma unroll
  for (int cc = 0; cc < 32; cc++){
    int c = cg + 4 * cc;
    mtf[((size_t)(bh * 8 + (c >> 4)) * 2 + ks) * 512 + ((c & 15) | lq) * 8 + el]
        = f2bf(inv * acc[cc]);
  }
}

// ---------------------------------------------------------------------------
// qout v4: 64-token tiles -> 1024 blocks (4/CU). Wave owns 16 tokens. NO smX
// (x B-frags hoisted to 4 regs, direct from pre-swizzled xt), ZERO barriers,
// LDS = 8 KiB wave-private smP only.
// ---------------------------------------------------------------------------
__global__ __launch_bounds__(256, 3) void qout(const u16* __restrict__ xt,
    const u16* __restrict__ wqf, const float* __restrict__ bqs,
    const u16* __restrict__ mtf, const float* __restrict__ bo,
    float* __restrict__ out){
  __shared__ u16 smP[4][16 * 64]; // per-wave p[16t][64d]  (8 KiB total)
  const int tid = threadIdx.x;
  const int tt = blockIdx.x, b = blockIdx.y;
  const int w = tid >> 6, l = tid & 63, r15 = l & 15, q = l >> 4;
  const int t0 = tt * 64;
  const int m7 = 2 * (r15 & 7);
  const int t = t0 + w * 16 + r15;

  // hoist x B-frags for this wave's 16 tokens (h-independent)
  bf16x8 xb[4];
#pragma unroll
  for (int ks = 0; ks < 4; ks++)
    xb[ks] = *(const bf16x8*)(xt + (size_t)(b * N_ + t) * 128 +
                              (((ks * 4 + q) ^ r15) * 8));

  u16* sp = smP[w];
  f32x4 acc3[8] = {};
  for (int h = 0; h < 8; h++){
    float bq_[4][4];
#pragma unroll
    for (int mi = 0; mi < 4; mi++){
      float4 v = *(const float4*)(bqs + h * 64 + 16 * mi + 4 * q);
      bq_[mi][0] = v.x; bq_[mi][1] = v.y; bq_[mi][2] = v.z; bq_[mi][3] = v.w;
    }
    // MFMA1: D[d 64][t 16], K=128; A = wq frags (global), B = xb (regs)
    f32x4 acc1[4] = {};
#pragma unroll
    for (int ks = 0; ks < 4; ks++){
      bf16x8 wqv[4];
#pragma unroll
      for (int mi = 0; mi < 4; mi++)
        wqv[mi] = *(const bf16x8*)(wqf +
            (size_t)((h * 4 + mi) * 4 + ks) * 512 + l * 8);
#pragma unroll
      for (int mi = 0; mi < 4; mi++)
        acc1[mi] = __builtin_amdgcn_mfma_f32_16x16x32_bf16(
            wqv[mi], xb[ks], acc1[mi], 0, 0, 0);
    }
    // exp + in-wave colsum + normalized p store (wave-private)
    {
      float ps = 0.f;
#pragma unroll
      for (int mi = 0; mi < 4; mi++)
#pragma unroll
        for (int r = 0; r < 4; r++){
          float e = __expf(acc1[mi][r] + bq_[mi][r]);
          acc1[mi][r] = e; ps += e;
        }
      ps += __shfl_xor(ps, 16); ps += __shfl_xor(ps, 32);
      const float ci = 1.f / ps;
#pragma unroll
      for (int mi = 0; mi < 4; mi++){
        uint2 pk;
        pk.x = pack2bf(acc1[mi][0] * ci, acc1[mi][1] * ci);
        pk.y = pack2bf(acc1[mi][2] * ci, acc1[mi][3] * ci);
        int g8s = (4 * mi + q) ^ m7;
        *(uint2*)&sp[r15 * 64 + g8s * 4] = pk;
      }
    }
    // MFMA2: out[c 128][t 16] += M_h · p, K=64
#pragma unroll
    for (int ks2 = 0; ks2 < 2; ks2++){
      const int g8s = (8 * ks2 + 2 * q) ^ m7;
      bf16x8 pb = *(const bf16x8*)&sp[r15 * 64 + g8s * 4];
#pragma unroll
      for (int half = 0; half < 2; half++){
        bf16x8 mf[4];
#pragma unroll
        for (int mm = 0; mm < 4; mm++)
          mf[mm] = *(const bf16x8*)(mtf +
              ((size_t)((b * 8 + h) * 8 + half * 4 + mm) * 2 + ks2) * 512 + l * 8);
#pragma unroll
        for (int mm = 0; mm < 4; mm++)
          acc3[half * 4 + mm] = __builtin_amdgcn_mfma_f32_16x16x32_bf16(
              mf[mm], pb, acc3[half * 4 + mm], 0, 0, 0);
      }
    }
  }
#pragma unroll
  for (int mi = 0; mi < 8; mi++){
    float4 bv = *(const float4*)(bo + 16 * mi + 4 * q);
    float bs[4] = {bv.x, bv.y, bv.z, bv.w};
#pragma unroll
    for (int r = 0; r < 4; r++){
      int c = 16 * mi + 4 * q + r;
      out[(size_t)(b * 128 + c) * N_ + t] = acc3[mi][r] + bs[r];
    }
  }
}

// ---------------------------------------------------------------------------
extern "C" void kernel_launch(void* const* d_in, const int* in_sizes, int n_in,
                              void* d_out, int out_size, void* d_ws, size_t ws_size,
                              hipStream_t stream){
  const float* x  = (const float*)d_in[0];
  const float* Wq = (const float*)d_in[1];
  const float* bq = (const float*)d_in[2];
  const float* Wk = (const float*)d_in[3];
  const float* bk = (const float*)d_in[4];
  const float* Wv = (const float*)d_in[5];
  const float* bv = (const float*)d_in[6];
  const float* Wo = (const float*)d_in[7];
  const float* bo = (const float*)d_in[8];
  float* out = (float*)d_out;

  char* ws = (char*)d_ws;
  u16*   xt     = (u16*)ws;                         // 16 MiB (pre-swizzled)
  u16*   wkvf   = (u16*)(ws + 16777216);            // 256 KiB
  u16*   wqf    = (u16*)(ws + 17039360);            // 128 KiB
  u16*   mtf    = (u16*)(ws + 17170432);            // 512 KiB
  float* bkv    = (float*)(ws + 17694720);          // 4 KiB
  float* bqs    = (float*)(ws + 17698816);          // 2 KiB
  float* rowsum = (float*)(ws + 17700864);          // 8 KiB
  float* ctx    = (float*)(ws + 17709056);          // 512 KiB
  float* pctx   = (float*)(ws + 18233344);          // 16 MiB
  float* prs    = (float*)(ws + 35010560);          // 512 KiB

  prep <<<96, 256, 0, stream>>>(Wq, bq, Wk, bk, Wv, bv, wkvf, wqf, bkv, bqs);
  convx<<<dim3(128, 4), 256, 0, stream>>>(x, xt);
  kvctx<<<dim3(32, 8, 4), 256, 0, stream>>>(xt, wkvf, bkv, pctx, prs);
  ctxred<<<dim3(32, 8), 256, 0, stream>>>(pctx, prs, ctx, rowsum);
  mker <<<dim3(8, 4), 256, 0, stream>>>(ctx, Wo, rowsum, mtf);
  qout <<<dim3(256, 4), 256, 0, stream>>>(xt, wqf, bqs, mtf, bo, out);
}